// Round 4
// baseline (501.585 us; speedup 1.0000x reference)
//
#include <hip/hip_runtime.h>
#include <hip/hip_bf16.h>

#define HH 64
#define TT 512
#define BB 16

typedef __attribute__((ext_vector_type(8))) short short8;
typedef __attribute__((ext_vector_type(4))) float f32x4;

static __device__ __forceinline__ unsigned short f2bf(float f) {
  unsigned u = __float_as_uint(f);
  u += 0x7fffu + ((u >> 16) & 1u);   // RNE (one-time weight pack only)
  return (unsigned short)(u >> 16);
}

static __device__ __forceinline__ float sigm(float x) {
  float e = __builtin_amdgcn_exp2f(-1.442695041f * x);
  return __builtin_amdgcn_rcpf(1.0f + e);
}
static __device__ __forceinline__ float tanh_fast(float x) {
  float e = __builtin_amdgcn_exp2f(2.885390082f * x);
  return 1.0f - 2.0f * __builtin_amdgcn_rcpf(1.0f + e);
}

static __device__ __forceinline__ short8 pack8(const float* __restrict__ p) {
  const float4* p4 = (const float4*)p;
  float4 a = p4[0], b = p4[1];
  short8 r;
  r[0] = (short)f2bf(a.x); r[1] = (short)f2bf(a.y);
  r[2] = (short)f2bf(a.z); r[3] = (short)f2bf(a.w);
  r[4] = (short)f2bf(b.x); r[5] = (short)f2bf(b.y);
  r[6] = (short)f2bf(b.z); r[7] = (short)f2bf(b.w);
  return r;
}

#define MF(A, B, C) __builtin_amdgcn_mfma_f32_16x16x32_bf16((A), (B), (C), 0, 0, 0)

// Spin until all 4 flags in fa >= ta AND all 4 in fb >= tb. Lane-uniform.
static __device__ __forceinline__ void spin2(volatile int* fa, int ta,
                                             volatile int* fb, int tb) {
  for (;;) {
    int a0 = fa[0], a1 = fa[1], a2 = fa[2], a3 = fa[3];
    int b0 = fb[0], b1 = fb[1], b2 = fb[2], b3 = fb[3];
    if (((a0 >= ta) & (a1 >= ta) & (a2 >= ta) & (a3 >= ta) &
         (b0 >= tb) & (b1 >= tb) & (b2 >= tb) & (b3 >= tb)) != 0)
      break;
  }
  asm volatile("" ::: "memory");   // acquire: keep data reads below the spin
}

// Ensure this wave's LDS writes are complete, then publish progress.
#define PUBLISH(FLAGP, VAL) {                                   \
    asm volatile("s_waitcnt lgkmcnt(0)" ::: "memory");          \
    if (lane == 0) *(volatile int*)(FLAGP) = (VAL);             \
  }

// ---- one LSTM-layer-0 step. Reads h0 ring slot RD, writes slot WR.
#define STEP_A(RD, WR) {                                                       \
    const char* rd = (const char*)(RD);                                        \
    short8 af0 = *(const short8*)(rd + rdo0);                                  \
    short8 af1 = *(const short8*)(rd + rdo1);                                  \
    f32x4 xv = *(const f32x4*)(xp); xp += BB;                                  \
    f32x4 a0 = MF(af0, wf[0], bs[0]); a0 = MF(af1, wf[1], a0);                 \
    f32x4 a1 = MF(af0, wf[2], bs[1]); a1 = MF(af1, wf[3], a1);                 \
    f32x4 a2 = MF(af0, wf[4], bs[2]); a2 = MF(af1, wf[5], a2);                 \
    f32x4 a3 = MF(af0, wf[6], bs[3]); a3 = MF(af1, wf[7], a3);                 \
    char* wrb = (char*)(WR);                                                   \
    _Pragma("unroll")                                                          \
    for (int j = 0; j < 4; ++j) {                                              \
      float pi = fmaf(xv[j], wx[0], a0[j]);                                    \
      float pf = fmaf(xv[j], wx[1], a1[j]);                                    \
      float pg = fmaf(xv[j], wx[2], a2[j]);                                    \
      float po = fmaf(xv[j], wx[3], a3[j]);                                    \
      float iv = sigm(pi), fv = sigm(pf);                                      \
      float gv = tanh_fast(pg), ov = sigm(po);                                 \
      float c = fmaf(fv, cst[j], iv * gv);                                     \
      cst[j] = c;                                                              \
      float h = ov * tanh_fast(c);                                             \
      *(__hip_bfloat16*)(wrb + wro[j]) = __float2bfloat16(h);                  \
    }                                                                          \
  }

// ---- one LSTM-layer-1 step. RD0: h0 ring slot (input); RD1/WR: h1 dbuf.
#define STEP_B(RD0, RD1, WR, LAST) {                                           \
    const char* rd0 = (const char*)(RD0);                                      \
    const char* rd1 = (const char*)(RD1);                                      \
    short8 af0 = *(const short8*)(rd0 + rdo0);                                 \
    short8 af1 = *(const short8*)(rd0 + rdo1);                                 \
    short8 af2 = *(const short8*)(rd1 + rdo0);                                 \
    short8 af3 = *(const short8*)(rd1 + rdo1);                                 \
    f32x4 a0 = MF(af0, wf[0],  bs[0]); a0 = MF(af1, wf[1],  a0);               \
    a0 = MF(af2, wf[2],  a0);  a0 = MF(af3, wf[3],  a0);                       \
    f32x4 a1 = MF(af0, wf[4],  bs[1]); a1 = MF(af1, wf[5],  a1);               \
    a1 = MF(af2, wf[6],  a1);  a1 = MF(af3, wf[7],  a1);                       \
    f32x4 a2 = MF(af0, wf[8],  bs[2]); a2 = MF(af1, wf[9],  a2);               \
    a2 = MF(af2, wf[10], a2);  a2 = MF(af3, wf[11], a2);                       \
    f32x4 a3 = MF(af0, wf[12], bs[3]); a3 = MF(af1, wf[13], a3);               \
    a3 = MF(af2, wf[14], a3);  a3 = MF(af3, wf[15], a3);                       \
    char* wrb = (char*)(WR);                                                   \
    _Pragma("unroll")                                                          \
    for (int j = 0; j < 4; ++j) {                                              \
      float iv = sigm(a0[j]), fv = sigm(a1[j]);                                \
      float gv = tanh_fast(a2[j]), ov = sigm(a3[j]);                           \
      float c = fmaf(fv, cst[j], iv * gv);                                     \
      cst[j] = c;                                                              \
      float h = ov * tanh_fast(c);                                             \
      *(__hip_bfloat16*)(wrb + wro[j]) = __float2bfloat16(h);                  \
      if (LAST) h1f[(q * 4 + j) * HH + colw] = h;                              \
    }                                                                          \
  }

__global__ __launch_bounds__(512, 2)
void lstm2_fused(const float* __restrict__ x,
                 const float* __restrict__ Wih0, const float* __restrict__ Whh0,
                 const float* __restrict__ bih0, const float* __restrict__ bhh0,
                 const float* __restrict__ Wih1, const float* __restrict__ Whh1,
                 const float* __restrict__ bih1, const float* __restrict__ bhh1,
                 const float* __restrict__ Wfc,  const float* __restrict__ bfc,
                 float* __restrict__ out)
{
  __shared__ float xs[TT * BB];                                // 32 KB, xs[t][row]
  __shared__ __align__(16) unsigned short h0ring[4][BB * HH];  // 8 KB ring, swizzled
  __shared__ __align__(16) unsigned short h1buf[2][BB * HH];   // 4 KB dbuf
  __shared__ float h1f[BB * HH];                               // fp32 final h1
  __shared__ int flagA[4], flagB[4];                           // per-wave progress

  const int tid  = threadIdx.x;
  const int wave = tid >> 6;
  const int lane = tid & 63;
  const int grp  = wave >> 2;      // 0: layer0 (4 waves), 1: layer1 (4 waves)
  const int w    = wave & 3;       // column-block 0..3
  const int m    = lane & 15;
  const int q    = lane >> 4;
  const int b0   = blockIdx.x * BB;

  // ---- stage x transposed: xs[t][r] = x[b0+r][t] ----
  {
    const int t = tid;             // blockDim.x == 512 == TT
    #pragma unroll
    for (int r = 0; r < BB; ++r)
      xs[t * BB + r] = x[(size_t)(b0 + r) * TT + t];
  }
  // zero h state (bf16 zero == 0x0000): ring = 2048 u32, h1buf = 1024 u32
  ((unsigned int*)h0ring)[tid]        = 0; ((unsigned int*)h0ring)[tid + 512]  = 0;
  ((unsigned int*)h0ring)[tid + 1024] = 0; ((unsigned int*)h0ring)[tid + 1536] = 0;
  ((unsigned int*)h1buf)[tid] = 0; ((unsigned int*)h1buf)[tid + 512] = 0;
  if (tid < 4) { flagA[tid] = 0; flagB[tid] = 0; }

  // ---- pack weight B-fragments into registers (held across the whole loop) ----
  // wave w owns gate n-tiles {4n+w}: n=0->i,1->f,2->g,3->o, cols 16w..16w+15.
  short8 wf[16];
  f32x4 bs[4];
  float wx[4];
  #pragma unroll
  for (int n = 0; n < 4; ++n) {
    const int colg = 16 * (4 * n + w) + m;
    if (grp == 0) {
      const float b = bih0[colg] + bhh0[colg];
      bs[n][0] = b; bs[n][1] = b; bs[n][2] = b; bs[n][3] = b;
      wx[n] = Wih0[colg];
      #pragma unroll
      for (int kt = 0; kt < 2; ++kt)
        wf[n * 2 + kt] = pack8(Whh0 + colg * HH + kt * 32 + q * 8);
    } else {
      const float b = bih1[colg] + bhh1[colg];
      bs[n][0] = b; bs[n][1] = b; bs[n][2] = b; bs[n][3] = b;
      wx[n] = 0.f;
      #pragma unroll
      for (int kt = 0; kt < 4; ++kt) {   // kt 0,1: Wih1 (h0 input); kt 2,3: Whh1
        const float* Wsrc = (kt < 2) ? Wih1 : Whh1;
        wf[n * 4 + kt] = pack8(Wsrc + colg * HH + (kt & 1) * 32 + q * 8);
      }
    }
  }

  // ---- loop-invariant LDS byte offsets (swizzle: 16B blocks XOR (row&7)<<4) ----
  const int colw = 16 * w + m;     // my h column within [0,64)
  const int rdo0 = m * 128 + ((q * 16) ^ ((m & 7) << 4));        // kt=0 A-frag
  const int rdo1 = m * 128 + ((64 + q * 16) ^ ((m & 7) << 4));   // kt=1 A-frag
  int wro[4];
  #pragma unroll
  for (int j = 0; j < 4; ++j) {
    const int row = q * 4 + j;
    wro[j] = row * 128 + ((2 * colw) ^ ((row & 7) << 4));
  }

  __syncthreads();   // x staged + h/flags zeroed — the ONLY barrier before epilogue

  float cst[4] = {0.f, 0.f, 0.f, 0.f};

  // Dependency-flag pipeline, no barriers in the loop:
  //   flagA[w] = #completed L0 steps by A-wave w (h0(t) ready <=> flagA_all >= t+1)
  //   flagB[w] = #completed L1 iters by B-wave w (iter t = L1 step t-1)
  // A step t: needs h0(t-1) [flagA>=t]; overwrites ring slot t&3 = h0(t-4),
  //   last read by B iter t-3 [flagB>=t-3].
  // B iter t: needs h0(t-1) [flagA>=t]; h1 dbuf anti-dep [flagB>=t-1].
  if (grp == 0) {
    const float* xp = xs + q * 4;
    #pragma unroll 1
    for (int k = 0; k < TT / 4; ++k) {
      const int t0 = 4 * k;
      spin2(flagA, t0,     flagB, t0 - 3);
      STEP_A(h0ring[3], h0ring[0])  PUBLISH(&flagA[w], t0 + 1);
      spin2(flagA, t0 + 1, flagB, t0 - 2);
      STEP_A(h0ring[0], h0ring[1])  PUBLISH(&flagA[w], t0 + 2);
      spin2(flagA, t0 + 2, flagB, t0 - 1);
      STEP_A(h0ring[1], h0ring[2])  PUBLISH(&flagA[w], t0 + 3);
      spin2(flagA, t0 + 3, flagB, t0);
      STEP_A(h0ring[2], h0ring[3])  PUBLISH(&flagA[w], t0 + 4);
    }
  } else {
    #pragma unroll 1
    for (int k = 0; k < TT / 4; ++k) {
      const int t1 = 4 * k + 1;
      const bool last = (k == TT / 4 - 1);
      spin2(flagA, t1,     flagB, t1 - 1);
      STEP_B(h0ring[0], h1buf[1], h1buf[0], false)  PUBLISH(&flagB[w], t1);
      spin2(flagA, t1 + 1, flagB, t1);
      STEP_B(h0ring[1], h1buf[0], h1buf[1], false)  PUBLISH(&flagB[w], t1 + 1);
      spin2(flagA, t1 + 2, flagB, t1 + 1);
      STEP_B(h0ring[2], h1buf[1], h1buf[0], false)  PUBLISH(&flagB[w], t1 + 2);
      spin2(flagA, t1 + 3, flagB, t1 + 2);
      STEP_B(h0ring[3], h1buf[0], h1buf[1], last)   PUBLISH(&flagB[w], t1 + 3);
    }
  }

  __syncthreads();   // h1f complete

  // ---- FC epilogue: out[b][o] = h1_final[b] . Wfc[o] + bfc[o] ----
  if (tid < BB * 7) {
    const int b = tid / 7, o = tid % 7;
    float s = bfc[o];
    #pragma unroll
    for (int k = 0; k < HH; ++k) s = fmaf(h1f[b * HH + k], Wfc[o * HH + k], s);
    out[(size_t)(b0 + b) * 7 + o] = s;
  }
}

extern "C" void kernel_launch(void* const* d_in, const int* in_sizes, int n_in,
                              void* d_out, int out_size, void* d_ws, size_t ws_size,
                              hipStream_t stream) {
  const float* x    = (const float*)d_in[0];
  const float* Wih0 = (const float*)d_in[1];
  const float* Whh0 = (const float*)d_in[2];
  const float* bih0 = (const float*)d_in[3];
  const float* bhh0 = (const float*)d_in[4];
  const float* Wih1 = (const float*)d_in[5];
  const float* Whh1 = (const float*)d_in[6];
  const float* bih1 = (const float*)d_in[7];
  const float* bhh1 = (const float*)d_in[8];
  const float* Wfc  = (const float*)d_in[9];
  const float* bfc  = (const float*)d_in[10];
  float* out = (float*)d_out;

  dim3 grid(4096 / BB);   // 256 workgroups, 1 per CU
  dim3 block(512);        // 8 waves: 4 layer-0 + 4 layer-1, flag-pipelined
  hipLaunchKernelGGL(lstm2_fused, grid, block, 0, stream,
                     x, Wih0, Whh0, bih0, bhh0, Wih1, Whh1, bih1, bhh1, Wfc, bfc, out);
}

// Round 5
// 426.273 us; speedup vs baseline: 1.1767x; 1.1767x over previous
//
#include <hip/hip_runtime.h>
#include <hip/hip_bf16.h>

#define HH 64
#define TT 512
#define BB 8     // batch rows per WG; batch row b lives at MFMA M-row 2b

typedef __attribute__((ext_vector_type(8))) short short8;
typedef __attribute__((ext_vector_type(4))) float f32x4;

static __device__ __forceinline__ unsigned short f2bf(float f) {
  unsigned u = __float_as_uint(f);
  u += 0x7fffu + ((u >> 16) & 1u);   // RNE (one-time weight pack only)
  return (unsigned short)(u >> 16);
}

static __device__ __forceinline__ float sigm(float x) {
  float e = __builtin_amdgcn_exp2f(-1.442695041f * x);
  return __builtin_amdgcn_rcpf(1.0f + e);
}
static __device__ __forceinline__ float tanh_fast(float x) {
  float e = __builtin_amdgcn_exp2f(2.885390082f * x);
  return 1.0f - 2.0f * __builtin_amdgcn_rcpf(1.0f + e);
}

static __device__ __forceinline__ short8 pack8(const float* __restrict__ p) {
  const float4* p4 = (const float4*)p;
  float4 a = p4[0], b = p4[1];
  short8 r;
  r[0] = (short)f2bf(a.x); r[1] = (short)f2bf(a.y);
  r[2] = (short)f2bf(a.z); r[3] = (short)f2bf(a.w);
  r[4] = (short)f2bf(b.x); r[5] = (short)f2bf(b.y);
  r[6] = (short)f2bf(b.z); r[7] = (short)f2bf(b.w);
  return r;
}

#define MF(A, B, C) __builtin_amdgcn_mfma_f32_16x16x32_bf16((A), (B), (C), 0, 0, 0)

// Activation for one valid accumulator slot J (compile-time 0 or 2).
// Batch row = 2q + J/2, M-row = 4q + J. CSTv = register holding this row's c.
#define ACT_STORE(A0, A1, A2, A3, J, XV, HASX, CSTv, WROv, WRB, LASTF) {       \
    float pi = (A0)[J], pf = (A1)[J], pg = (A2)[J], po = (A3)[J];              \
    if (HASX) {                                                                \
      pi = fmaf((XV), wx[0], pi); pf = fmaf((XV), wx[1], pf);                  \
      pg = fmaf((XV), wx[2], pg); po = fmaf((XV), wx[3], po);                  \
    }                                                                          \
    float iv = sigm(pi), fv = sigm(pf);                                        \
    float gv = tanh_fast(pg), ov = sigm(po);                                   \
    float c = fmaf(fv, (CSTv), iv * gv);                                       \
    (CSTv) = c;                                                                \
    float h = ov * tanh_fast(c);                                               \
    *(__hip_bfloat16*)((WRB) + (WROv)) = __float2bfloat16(h);                  \
    if (LASTF) h1f[(2 * q + (J) / 2) * HH + colw] = h;                         \
  }

// ---- one LSTM-layer-0 step, phase P. Reads h0buf[P^1], writes h0buf[P].
#define STEP_A(P) {                                                            \
    const char* rd = (const char*)h0buf[(P) ^ 1];                              \
    short8 af0 = *(const short8*)(rd + rdo0);                                  \
    short8 af1 = *(const short8*)(rd + rdo1);                                  \
    float2 xv = *(const float2*)xpf; xpf += BB;                                \
    f32x4 a0 = MF(af0, wf[0], bs[0]); a0 = MF(af1, wf[1], a0);                 \
    f32x4 a1 = MF(af0, wf[2], bs[1]); a1 = MF(af1, wf[3], a1);                 \
    f32x4 a2 = MF(af0, wf[4], bs[2]); a2 = MF(af1, wf[5], a2);                 \
    f32x4 a3 = MF(af0, wf[6], bs[3]); a3 = MF(af1, wf[7], a3);                 \
    char* wrb = (char*)h0buf[P];                                               \
    ACT_STORE(a0, a1, a2, a3, 0, xv.x, true, cst0, wro0, wrb, false)           \
    ACT_STORE(a0, a1, a2, a3, 2, xv.y, true, cst1, wro1, wrb, false)           \
  }

// ---- one LSTM-layer-1 step, phase P. Reads h0buf[P^1] + h1buf[P], writes h1buf[P^1].
#define STEP_B(P, LAST) {                                                      \
    const char* rd0 = (const char*)h0buf[(P) ^ 1];                             \
    const char* rd1 = (const char*)h1buf[P];                                   \
    short8 af0 = *(const short8*)(rd0 + rdo0);                                 \
    short8 af1 = *(const short8*)(rd0 + rdo1);                                 \
    short8 af2 = *(const short8*)(rd1 + rdo0);                                 \
    short8 af3 = *(const short8*)(rd1 + rdo1);                                 \
    f32x4 a0 = MF(af0, wf[0],  bs[0]); a0 = MF(af1, wf[1],  a0);               \
    a0 = MF(af2, wf[2],  a0);  a0 = MF(af3, wf[3],  a0);                       \
    f32x4 a1 = MF(af0, wf[4],  bs[1]); a1 = MF(af1, wf[5],  a1);               \
    a1 = MF(af2, wf[6],  a1);  a1 = MF(af3, wf[7],  a1);                       \
    f32x4 a2 = MF(af0, wf[8],  bs[2]); a2 = MF(af1, wf[9],  a2);               \
    a2 = MF(af2, wf[10], a2);  a2 = MF(af3, wf[11], a2);                       \
    f32x4 a3 = MF(af0, wf[12], bs[3]); a3 = MF(af1, wf[13], a3);               \
    a3 = MF(af2, wf[14], a3);  a3 = MF(af3, wf[15], a3);                       \
    char* wrb = (char*)h1buf[(P) ^ 1];                                         \
    ACT_STORE(a0, a1, a2, a3, 0, 0.f, false, cst0, wro0, wrb, LAST)            \
    ACT_STORE(a0, a1, a2, a3, 2, 0.f, false, cst1, wro1, wrb, LAST)            \
  }

__global__ __launch_bounds__(512, 4)
void lstm2_fused(const float* __restrict__ x,
                 const float* __restrict__ Wih0, const float* __restrict__ Whh0,
                 const float* __restrict__ bih0, const float* __restrict__ bhh0,
                 const float* __restrict__ Wih1, const float* __restrict__ Whh1,
                 const float* __restrict__ bih1, const float* __restrict__ bhh1,
                 const float* __restrict__ Wfc,  const float* __restrict__ bfc,
                 float* __restrict__ out)
{
  __shared__ float xs[TT * BB];                               // 16 KB, xs[t][row]
  __shared__ __align__(16) unsigned short h0buf[2][16 * HH];  // dbuf bf16, swizzled
  __shared__ __align__(16) unsigned short h1buf[2][16 * HH];  // (odd M-rows stay 0)
  __shared__ float h1f[BB * HH];                              // fp32 final h1

  const int tid  = threadIdx.x;
  const int wave = tid >> 6;
  const int lane = tid & 63;
  const int grp  = wave >> 2;      // 0: layer0 (4 waves), 1: layer1 (4 waves)
  const int w    = wave & 3;       // column-block 0..3
  const int m    = lane & 15;
  const int q    = lane >> 4;
  const int b0   = blockIdx.x * BB;

  // ---- stage x transposed: xs[t][r] = x[b0+r][t] ----
  {
    const int t = tid;             // blockDim.x == 512 == TT
    #pragma unroll
    for (int r = 0; r < BB; ++r)
      xs[t * BB + r] = x[(size_t)(b0 + r) * TT + t];
  }
  // zero h state (bf16 zero == 0x0000): each dbuf pair = 1024 u32
  ((unsigned int*)h0buf)[tid] = 0; ((unsigned int*)h0buf)[tid + 512] = 0;
  ((unsigned int*)h1buf)[tid] = 0; ((unsigned int*)h1buf)[tid + 512] = 0;

  // ---- pack weight B-fragments into registers (held across the whole loop) ----
  // wave w owns gate n-tiles {4n+w}: n=0->i,1->f,2->g,3->o, cols 16w..16w+15.
  short8 wf[16];
  f32x4 bs[4];
  float wx[4];
  #pragma unroll
  for (int n = 0; n < 4; ++n) {
    const int colg = 16 * (4 * n + w) + m;
    if (grp == 0) {
      const float b = bih0[colg] + bhh0[colg];
      bs[n][0] = b; bs[n][1] = b; bs[n][2] = b; bs[n][3] = b;
      wx[n] = Wih0[colg];
      #pragma unroll
      for (int kt = 0; kt < 2; ++kt)
        wf[n * 2 + kt] = pack8(Whh0 + colg * HH + kt * 32 + q * 8);
    } else {
      const float b = bih1[colg] + bhh1[colg];
      bs[n][0] = b; bs[n][1] = b; bs[n][2] = b; bs[n][3] = b;
      wx[n] = 0.f;
      #pragma unroll
      for (int kt = 0; kt < 4; ++kt) {   // kt 0,1: Wih1 (h0 input); kt 2,3: Whh1
        const float* Wsrc = (kt < 2) ? Wih1 : Whh1;
        wf[n * 4 + kt] = pack8(Wsrc + colg * HH + (kt & 1) * 32 + q * 8);
      }
    }
  }

  // ---- loop-invariant LDS byte offsets (swizzle: 16B blocks XOR (row&7)<<4) ----
  const int colw = 16 * w + m;     // my h column within [0,64)
  const int rdo0 = m * 128 + ((q * 16) ^ ((m & 7) << 4));        // kt=0 A-frag
  const int rdo1 = m * 128 + ((64 + q * 16) ^ ((m & 7) << 4));   // kt=1 A-frag
  const int r0 = 4 * q;            // M-row for acc slot j=0 (batch row 2q)
  const int r2 = 4 * q + 2;        // M-row for acc slot j=2 (batch row 2q+1)
  const int wro0 = r0 * 128 + ((2 * colw) ^ ((r0 & 7) << 4));
  const int wro1 = r2 * 128 + ((2 * colw) ^ ((r2 & 7) << 4));

  __syncthreads();   // x staged + h zeroed

  float cst0 = 0.f, cst1 = 0.f;
  const float* xpf = xs + 2 * q;   // float2 covers batch rows 2q, 2q+1

  // Iteration t (phase P = t&1): A computes L0 step t (t<TT);
  // B computes L1 step t-1 (t>=1). ONE barrier per step.
  if (grp == 0) { STEP_A(0) }      // t=0 peel
  __syncthreads();

  #pragma unroll 1
  for (int k = 0; k < (TT - 2) / 2; ++k) {   // t = 1..510
    if (grp == 0) { STEP_A(1) } else { STEP_B(1, false) }
    __syncthreads();
    if (grp == 0) { STEP_A(0) } else { STEP_B(0, false) }
    __syncthreads();
  }
  // t=511 (P=1): both.
  if (grp == 0) { STEP_A(1) } else { STEP_B(1, false) }
  __syncthreads();
  // t=512 (P=0): B only, final h1 spilled to fp32.
  if (grp == 1) { STEP_B(0, true) }
  __syncthreads();

  // ---- FC epilogue: out[b][o] = h1_final[b] . Wfc[o] + bfc[o] ----
  if (tid < BB * 7) {
    const int b = tid / 7, o = tid % 7;
    float s = bfc[o];
    #pragma unroll
    for (int k = 0; k < HH; ++k) s = fmaf(h1f[b * HH + k], Wfc[o * HH + k], s);
    out[(size_t)(b0 + b) * 7 + o] = s;
  }
}

extern "C" void kernel_launch(void* const* d_in, const int* in_sizes, int n_in,
                              void* d_out, int out_size, void* d_ws, size_t ws_size,
                              hipStream_t stream) {
  const float* x    = (const float*)d_in[0];
  const float* Wih0 = (const float*)d_in[1];
  const float* Whh0 = (const float*)d_in[2];
  const float* bih0 = (const float*)d_in[3];
  const float* bhh0 = (const float*)d_in[4];
  const float* Wih1 = (const float*)d_in[5];
  const float* Whh1 = (const float*)d_in[6];
  const float* bih1 = (const float*)d_in[7];
  const float* bhh1 = (const float*)d_in[8];
  const float* Wfc  = (const float*)d_in[9];
  const float* bfc  = (const float*)d_in[10];
  float* out = (float*)d_out;

  dim3 grid(4096 / BB);   // 512 workgroups -> 2 independent WGs per CU
  dim3 block(512);        // 8 waves: 4 layer-0 + 4 layer-1, pipelined
  hipLaunchKernelGGL(lstm2_fused, grid, block, 0, stream,
                     x, Wih0, Whh0, bih0, bhh0, Wih1, Whh1, bih1, bhh1, Wfc, bfc, out);
}